// Round 4
// baseline (27567.520 us; speedup 1.0000x reference)
//
#include <hip/hip_runtime.h>
#include <hip/hip_bf16.h>

// Problem dims
constexpr int kH  = 2048;          // hidden
constexpr int kD  = 1024;          // input dim
constexpr int kT  = 4096;          // timesteps
constexpr int kTH = 3 * kH;        // 6144 gate rows
constexpr int kNB = 256;           // GRU grid blocks (128 per sequence)

// ---------------------------------------------------------------------------
// Round-10 ended in "container failed twice" with no profile. Protocol
// re-audit found no deadlock (publish-before-poll => progress; 2-step
// separation => no overwrite of pending reads). Most likely infra flake.
// Round-11 = identical design, HANG-PROOFED: all tag checks are >= instead
// of ==. Tags are monotone, so under the no-overwrite invariant behavior is
// bit-identical; if the invariant were ever violated on HW, the kernel now
// finishes with detectable wrong output instead of hanging the container.
// Design recap:
//  * producer: each wave owns complete {r,z,n} row triples for 2 h-elems
//    (row g*kH + i0 + wv*2 + jj). After its OWN shfl_down reduce, lane 0
//    computes both elems' gates and fire-and-forget publishes tagged words
//    {tag=t+1 | f32}. No hp_s exchange, no vmcnt(0), no flag array.
//  * consumer: wave 0 sentinel-polls one tag per block (128 words, 2/lane;
//    word i0 of each block is that block's own wave-0 publish), then
//    barrier; all 512 threads bulk-load the 2048 tagged words once with
//    per-word verify + selective retry (first try almost always hits: the
//    sentinel already absorbed the visibility latency).
// Numerics: per-row partial pattern (lane l covers cols e*256+4l..+3) and
// the shfl_down(32..1) tree are IDENTICAL to r7 -> bit-identical trajectory.
// ---------------------------------------------------------------------------

__global__ void init_pub_kernel(unsigned long long* __restrict__ pub) {
    // zero [2 seq][2 parity][kH] tagged words = 8192
    pub[blockIdx.x * 1024 + threadIdx.x] = 0ull;
}

// fp32 tiled GEMM: xp[t][j] = sum_k x[t][k] * Wih[j][k] + bih[j]
__global__ __launch_bounds__(256) void gemm_xp_kernel(
    const float* __restrict__ x1, const float* __restrict__ x2,
    const float* __restrict__ Wih1, const float* __restrict__ Wih2,
    const float* __restrict__ bih1, const float* __restrict__ bih2,
    float* __restrict__ xp1, float* __restrict__ xp2) {
    const float* x  = blockIdx.z ? x2   : x1;
    const float* W  = blockIdx.z ? Wih2 : Wih1;
    const float* bi = blockIdx.z ? bih2 : bih1;
    float*       xp = blockIdx.z ? xp2  : xp1;

    __shared__ float As[16][68];
    __shared__ float Bs[16][68];

    const int tid  = threadIdx.x;
    const int tx   = tid & 15, ty = tid >> 4;
    const int lrow = tid >> 2;
    const int lk   = (tid & 3) * 4;
    const int m0   = blockIdx.y * 64;
    const int n0   = blockIdx.x * 64;

    float acc[4][4] = {};

    for (int k0 = 0; k0 < kD; k0 += 16) {
        float4 av = *(const float4*)(x + (size_t)(m0 + lrow) * kD + k0 + lk);
        float4 bv = *(const float4*)(W + (size_t)(n0 + lrow) * kD + k0 + lk);
        __syncthreads();
        As[lk + 0][lrow] = av.x; As[lk + 1][lrow] = av.y;
        As[lk + 2][lrow] = av.z; As[lk + 3][lrow] = av.w;
        Bs[lk + 0][lrow] = bv.x; Bs[lk + 1][lrow] = bv.y;
        Bs[lk + 2][lrow] = bv.z; Bs[lk + 3][lrow] = bv.w;
        __syncthreads();
#pragma unroll
        for (int kk = 0; kk < 16; ++kk) {
            float4 a = *(const float4*)&As[kk][ty * 4];
            float4 b = *(const float4*)&Bs[kk][tx * 4];
            float aa[4] = {a.x, a.y, a.z, a.w};
            float bb[4] = {b.x, b.y, b.z, b.w};
#pragma unroll
            for (int i = 0; i < 4; ++i)
#pragma unroll
                for (int j = 0; j < 4; ++j)
                    acc[i][j] = fmaf(aa[i], bb[j], acc[i][j]);
        }
    }

    float4 bb4 = *(const float4*)(bi + n0 + tx * 4);
    float bArr[4] = {bb4.x, bb4.y, bb4.z, bb4.w};
#pragma unroll
    for (int i = 0; i < 4; ++i) {
        float4 o;
        o.x = acc[i][0] + bArr[0];
        o.y = acc[i][1] + bArr[1];
        o.z = acc[i][2] + bArr[2];
        o.w = acc[i][3] + bArr[3];
        *(float4*)(xp + (size_t)(m0 + ty * 4 + i) * kTH + n0 + tx * 4) = o;
    }
}

// Persistent GRU. 256 blocks x 512 threads, 1 block/CU.
// Block b: sequence s=b>>7, owns h[i0..i0+16), i0=(b&127)*16.
// Wave w owns rows {g*kH + i0 + 2w + jj : g in 0..2, jj in 0..1} -> complete
// gate triples for 2 elems; lane l covers cols e*256+4l..+3.
__global__ __launch_bounds__(512, 2) void gru_pair_kernel(
    const float* __restrict__ xp1, const float* __restrict__ xp2,
    const float* __restrict__ Whh1, const float* __restrict__ Whh2,
    const float* __restrict__ bhh1, const float* __restrict__ bhh2,
    unsigned long long* __restrict__ pub,   // [2 seq][2 parity][kH]
    float* __restrict__ hfinal) {           // [2 seq][kH]
    const int tid  = threadIdx.x;
    const int lane = tid & 63;
    const int wv   = tid >> 6;          // 0..7
    const int b    = blockIdx.x;
    const int s    = b >> 7;
    const int lb   = b & 127;
    const int i0   = lb * 16;
    const float* xp  = s ? xp2  : xp1;
    const float* Whh = s ? Whh2 : Whh1;
    const float* bhh = s ? bhh2 : bhh1;
    unsigned long long* pubs = pub + (size_t)s * 2 * kH;

    __shared__ float h_s[kH];
    __shared__ float xp_s[2][48];       // [parity][g*16+elem]

    // one-time register-resident weight load: p = g*2+jj
    float w[6][32];
    float bias[6];
#pragma unroll
    for (int p = 0; p < 6; ++p) {
        const int g  = p >> 1, jj = p & 1;
        const int rg = g * kH + i0 + wv * 2 + jj;
        bias[p] = bhh[rg];
        const float* wr = Whh + (size_t)rg * kH;
#pragma unroll
        for (int e = 0; e < 8; ++e) {
            float4 v = *(const float4*)(wr + e * 256 + lane * 4);
            w[p][e * 4 + 0] = v.x; w[p][e * 4 + 1] = v.y;
            w[p][e * 4 + 2] = v.z; w[p][e * 4 + 3] = v.w;
        }
    }
    *(float4*)&h_s[tid * 4] = make_float4(0.f, 0.f, 0.f, 0.f);
    if (tid < 48) {                     // stage xp[0]
        xp_s[0][tid] = xp[(size_t)(tid >> 4) * kH + i0 + (tid & 15)];
    }
    __syncthreads();

    const int base = tid * 4;

    for (int t = 0; t < kT; ++t) {
        const int parC = t & 1;
        const int parN = parC ^ 1;

        // wave 1: issue xp[t+1] loads early (latency hides under matvec)
        float xpv = 0.f;
        if (wv == 1 && lane < 48 && t + 1 < kT) {
            xpv = xp[(size_t)(t + 1) * kTH + (size_t)(lane >> 4) * kH + i0 +
                     (lane & 15)];
        }

        // matvec: 6 rows (3 gates x 2 elems), weights in regs, h from LDS
        float a0 = 0.f, a1 = 0.f, a2 = 0.f, a3 = 0.f, a4 = 0.f, a5 = 0.f;
#pragma unroll
        for (int e = 0; e < 8; ++e) {
            const float4 hv = *(const float4*)&h_s[e * 256 + lane * 4];
            a0 = fmaf(w[0][e * 4 + 0], hv.x, a0);
            a0 = fmaf(w[0][e * 4 + 1], hv.y, a0);
            a0 = fmaf(w[0][e * 4 + 2], hv.z, a0);
            a0 = fmaf(w[0][e * 4 + 3], hv.w, a0);
            a1 = fmaf(w[1][e * 4 + 0], hv.x, a1);
            a1 = fmaf(w[1][e * 4 + 1], hv.y, a1);
            a1 = fmaf(w[1][e * 4 + 2], hv.z, a1);
            a1 = fmaf(w[1][e * 4 + 3], hv.w, a1);
            a2 = fmaf(w[2][e * 4 + 0], hv.x, a2);
            a2 = fmaf(w[2][e * 4 + 1], hv.y, a2);
            a2 = fmaf(w[2][e * 4 + 2], hv.z, a2);
            a2 = fmaf(w[2][e * 4 + 3], hv.w, a2);
            a3 = fmaf(w[3][e * 4 + 0], hv.x, a3);
            a3 = fmaf(w[3][e * 4 + 1], hv.y, a3);
            a3 = fmaf(w[3][e * 4 + 2], hv.z, a3);
            a3 = fmaf(w[3][e * 4 + 3], hv.w, a3);
            a4 = fmaf(w[4][e * 4 + 0], hv.x, a4);
            a4 = fmaf(w[4][e * 4 + 1], hv.y, a4);
            a4 = fmaf(w[4][e * 4 + 2], hv.z, a4);
            a4 = fmaf(w[4][e * 4 + 3], hv.w, a4);
            a5 = fmaf(w[5][e * 4 + 0], hv.x, a5);
            a5 = fmaf(w[5][e * 4 + 1], hv.y, a5);
            a5 = fmaf(w[5][e * 4 + 2], hv.z, a5);
            a5 = fmaf(w[5][e * 4 + 3], hv.w, a5);
        }
        // shfl_down reduce (same tree as prior rounds -> bit-identical)
        float acc6[6] = {a0, a1, a2, a3, a4, a5};
#pragma unroll
        for (int p = 0; p < 6; ++p) {
            float a = acc6[p];
#pragma unroll
            for (int off = 32; off; off >>= 1) a += __shfl_down(a, off, 64);
            acc6[p] = a;                // valid on lane 0
        }

        unsigned long long* dst = pubs + (size_t)parN * kH;
        if (lane == 0) {
            // gates for this wave's 2 elems + fire-and-forget tagged publish
#pragma unroll
            for (int jj = 0; jj < 2; ++jj) {
                const int le = wv * 2 + jj;       // local elem 0..15
                const int i  = i0 + le;
                const float hr = acc6[0 + jj] + bias[0 + jj];
                const float hz = acc6[2 + jj] + bias[2 + jj];
                const float hnp = acc6[4 + jj] + bias[4 + jj];
                const float xr = xp_s[parC][le];
                const float xz = xp_s[parC][16 + le];
                const float xn = xp_s[parC][32 + le];
                const float r = 1.f / (1.f + expf(-(xr + hr)));
                const float z = 1.f / (1.f + expf(-(xz + hz)));
                const float n = tanhf(xn + r * hnp);
                const float hn = (1.f - z) * n + z * h_s[i];
                if (t == kT - 1) {
                    hfinal[s * kH + i] = hn;
                } else {
                    const unsigned long long pk =
                        ((unsigned long long)(unsigned)(t + 1) << 32) |
                        (unsigned long long)__float_as_uint(hn);
                    __hip_atomic_store(&dst[i], pk, __ATOMIC_RELAXED,
                                       __HIP_MEMORY_SCOPE_AGENT);
                }
            }
        }
        if (t == kT - 1) break;

        if (wv == 0) {
            // sentinel: one tag per block (word j*16, published by that
            // block's own wave 0); 128 words, 2 per lane. >= is hang-safe.
            const unsigned tgt = (unsigned)(t + 1);
            const unsigned long long* f0 = dst + (size_t)lane * 16;
            const unsigned long long* f1 = dst + (size_t)(lane + 64) * 16;
            for (;;) {
                const unsigned long long v0 = __hip_atomic_load(
                    f0, __ATOMIC_RELAXED, __HIP_MEMORY_SCOPE_AGENT);
                const unsigned long long v1 = __hip_atomic_load(
                    f1, __ATOMIC_RELAXED, __HIP_MEMORY_SCOPE_AGENT);
                if (__all(((unsigned)(v0 >> 32) >= tgt) &&
                          ((unsigned)(v1 >> 32) >= tgt)))
                    break;
                __builtin_amdgcn_s_sleep(1);
            }
        } else if (wv == 1) {
            if (lane < 48) xp_s[parN][lane] = xpv;
        }
        __syncthreads();   // (B) all publishes globally visible (sentinel)

        // bulk load: 4 tagged words/thread, verify (>=), selective retry
        {
            const unsigned tgt = (unsigned)(t + 1);
            unsigned long long v0, v1, v2, v3;
            v0 = __hip_atomic_load(&dst[base + 0], __ATOMIC_RELAXED,
                                   __HIP_MEMORY_SCOPE_AGENT);
            v1 = __hip_atomic_load(&dst[base + 1], __ATOMIC_RELAXED,
                                   __HIP_MEMORY_SCOPE_AGENT);
            v2 = __hip_atomic_load(&dst[base + 2], __ATOMIC_RELAXED,
                                   __HIP_MEMORY_SCOPE_AGENT);
            v3 = __hip_atomic_load(&dst[base + 3], __ATOMIC_RELAXED,
                                   __HIP_MEMORY_SCOPE_AGENT);
            bool d0 = (unsigned)(v0 >> 32) >= tgt;
            bool d1 = (unsigned)(v1 >> 32) >= tgt;
            bool d2 = (unsigned)(v2 >> 32) >= tgt;
            bool d3 = (unsigned)(v3 >> 32) >= tgt;
            while (!(d0 & d1 & d2 & d3)) {
                __builtin_amdgcn_s_sleep(1);
                if (!d0) { v0 = __hip_atomic_load(&dst[base + 0], __ATOMIC_RELAXED, __HIP_MEMORY_SCOPE_AGENT); d0 = (unsigned)(v0 >> 32) >= tgt; }
                if (!d1) { v1 = __hip_atomic_load(&dst[base + 1], __ATOMIC_RELAXED, __HIP_MEMORY_SCOPE_AGENT); d1 = (unsigned)(v1 >> 32) >= tgt; }
                if (!d2) { v2 = __hip_atomic_load(&dst[base + 2], __ATOMIC_RELAXED, __HIP_MEMORY_SCOPE_AGENT); d2 = (unsigned)(v2 >> 32) >= tgt; }
                if (!d3) { v3 = __hip_atomic_load(&dst[base + 3], __ATOMIC_RELAXED, __HIP_MEMORY_SCOPE_AGENT); d3 = (unsigned)(v3 >> 32) >= tgt; }
            }
            float4 hv;
            hv.x = __uint_as_float((unsigned)v0);
            hv.y = __uint_as_float((unsigned)v1);
            hv.z = __uint_as_float((unsigned)v2);
            hv.w = __uint_as_float((unsigned)v3);
            *(float4*)&h_s[base] = hv;
        }
        __syncthreads();   // (C) h_s ready for next matvec
    }
}

// fc1(relu) -> fc2 -> log_softmax, single block of 256 threads
__global__ __launch_bounds__(256) void head_kernel(
    const float* __restrict__ h1, const float* __restrict__ h2,
    const float* __restrict__ fc1w, const float* __restrict__ fc1b,
    const float* __restrict__ fc2w, const float* __restrict__ fc2b,
    float* __restrict__ out) {
    __shared__ float cat[2 * kH];
    __shared__ float o1[256];
    __shared__ float logits[3];
    const int tid  = threadIdx.x;
    const int lane = tid & 63;
    const int wave = tid >> 6;

    for (int k = tid; k < kH; k += 256) {
        cat[k]      = h1[k];
        cat[kH + k] = h2[k];
    }
    __syncthreads();

    for (int r = wave; r < 256; r += 4) {
        const float* wr = fc1w + (size_t)r * (2 * kH);
        float acc = 0.f;
        for (int j = lane; j < 2 * kH; j += 64) acc = fmaf(wr[j], cat[j], acc);
#pragma unroll
        for (int off = 32; off; off >>= 1) acc += __shfl_down(acc, off, 64);
        if (lane == 0) o1[r] = fmaxf(acc + fc1b[r], 0.f);
    }
    __syncthreads();

    if (tid < 3) {
        float acc = fc2b[tid];
        const float* wr = fc2w + tid * 256;
        for (int j = 0; j < 256; ++j) acc = fmaf(wr[j], o1[j], acc);
        logits[tid] = acc;
    }
    __syncthreads();

    if (tid == 0) {
        float m = fmaxf(logits[0], fmaxf(logits[1], logits[2]));
        float s = expf(logits[0] - m) + expf(logits[1] - m) + expf(logits[2] - m);
        float ls = logf(s);
        out[0] = logits[0] - m - ls;
        out[1] = logits[1] - m - ls;
        out[2] = logits[2] - m - ls;
    }
}

extern "C" void kernel_launch(void* const* d_in, const int* in_sizes, int n_in,
                              void* d_out, int out_size, void* d_ws,
                              size_t ws_size, hipStream_t stream) {
    const float* x1   = (const float*)d_in[0];
    const float* x2   = (const float*)d_in[1];
    const float* Wih1 = (const float*)d_in[2];
    const float* Whh1 = (const float*)d_in[3];
    const float* bih1 = (const float*)d_in[4];
    const float* bhh1 = (const float*)d_in[5];
    const float* Wih2 = (const float*)d_in[6];
    const float* Whh2 = (const float*)d_in[7];
    const float* bih2 = (const float*)d_in[8];
    const float* bhh2 = (const float*)d_in[9];
    const float* fc1w = (const float*)d_in[10];
    const float* fc1b = (const float*)d_in[11];
    const float* fc2w = (const float*)d_in[12];
    const float* fc2b = (const float*)d_in[13];
    float* out = (float*)d_out;

    char* ws = (char*)d_ws;
    float* xp1 = (float*)ws;
    float* xp2 = xp1 + (size_t)kT * kTH;
    unsigned long long* pub = (unsigned long long*)(xp2 + (size_t)kT * kTH);
    float* hfinal = (float*)(pub + 4 * kH);   // [2][kH]

    init_pub_kernel<<<8, 1024, 0, stream>>>(pub);

    gemm_xp_kernel<<<dim3(kTH / 64, kT / 64, 2), 256, 0, stream>>>(
        x1, x2, Wih1, Wih2, bih1, bih2, xp1, xp2);

    gru_pair_kernel<<<dim3(kNB), dim3(512), 0, stream>>>(
        xp1, xp2, Whh1, Whh2, bhh1, bhh2, pub, hfinal);

    head_kernel<<<1, 256, 0, stream>>>(hfinal, hfinal + kH, fc1w, fc1b, fc2w,
                                       fc2b, out);
}

// Round 5
// 19895.132 us; speedup vs baseline: 1.3856x; 1.3856x over previous
//
#include <hip/hip_runtime.h>
#include <hip/hip_bf16.h>

// Problem dims
constexpr int kH  = 2048;          // hidden
constexpr int kD  = 1024;          // input dim
constexpr int kT  = 4096;          // timesteps
constexpr int kTH = 3 * kH;        // 6144 gate rows
constexpr int kNB = 256;           // GRU grid blocks (128 per sequence)

// ---------------------------------------------------------------------------
// Round-11 post-mortem (24.5 ms, WRITE 524 MB = 4.1x published bytes):
// 8 waves each wrote a 16-B piece of the block's single 128-B pub line at
// different times WHILE 128 remote sentinels polled those same data lines ->
// every partial update re-dirtied the line, every remote poll forced a
// writeback. r8/r9/r11 all confirm: never poll the lines being written;
// never multi-wave piecewise-write a remotely-read line.
// Round-12 = r7's consumer (poll dedicated flag lines only, one bulk read)
// + parallel per-wave gates + drain-free producer:
//  * each wave owns complete {r,z,n} triples for 2 elems; after its own
//    shfl reduce, lanes 0-1 compute gates -> hn_s (LDS). Barrier A.
//  * wave 0 issues ONE coalesced 128-B tagged store (16 lanes x 8 B,
//    {tag=t+1 | f32}), then the flag store with NO vmcnt(0): the flag is
//    only a hint; correctness comes from per-word tag verify (>=) at the
//    bulk read. No producer drain on the critical path.
//  * wave 1 polls the 128 dedicated flag words (64-B stride, written once
//    per step); barrier B; all threads bulk-read 2048 tagged words once
//    with selective retry (first try ~always hits); LDS; barrier C.
// Hang-impossible: tags monotone + >= checks. 2-step separation proof:
// a word tagged t+1 is overwritten (tag t+3) only after its writer verified
// ALL blocks' t+2, which requires every block completed its step-t bulk
// read of t+1. Numerics: per-row partial pattern and shfl tree unchanged ->
// bit-identical trajectory (absmax 0.0).
// ---------------------------------------------------------------------------

__global__ void init_ws_kernel(unsigned long long* __restrict__ pub,
                               unsigned* __restrict__ sync) {
    const int i = blockIdx.x * 1024 + threadIdx.x;
    if (i < 8192) pub[i] = 0ull;        // [2 seq][2 parity][kH]
    if (i < 4096) sync[i] = 0u;         // flag lines, 64-B stride
}

// fp32 tiled GEMM: xp[t][j] = sum_k x[t][k] * Wih[j][k] + bih[j]
__global__ __launch_bounds__(256) void gemm_xp_kernel(
    const float* __restrict__ x1, const float* __restrict__ x2,
    const float* __restrict__ Wih1, const float* __restrict__ Wih2,
    const float* __restrict__ bih1, const float* __restrict__ bih2,
    float* __restrict__ xp1, float* __restrict__ xp2) {
    const float* x  = blockIdx.z ? x2   : x1;
    const float* W  = blockIdx.z ? Wih2 : Wih1;
    const float* bi = blockIdx.z ? bih2 : bih1;
    float*       xp = blockIdx.z ? xp2  : xp1;

    __shared__ float As[16][68];
    __shared__ float Bs[16][68];

    const int tid  = threadIdx.x;
    const int tx   = tid & 15, ty = tid >> 4;
    const int lrow = tid >> 2;
    const int lk   = (tid & 3) * 4;
    const int m0   = blockIdx.y * 64;
    const int n0   = blockIdx.x * 64;

    float acc[4][4] = {};

    for (int k0 = 0; k0 < kD; k0 += 16) {
        float4 av = *(const float4*)(x + (size_t)(m0 + lrow) * kD + k0 + lk);
        float4 bv = *(const float4*)(W + (size_t)(n0 + lrow) * kD + k0 + lk);
        __syncthreads();
        As[lk + 0][lrow] = av.x; As[lk + 1][lrow] = av.y;
        As[lk + 2][lrow] = av.z; As[lk + 3][lrow] = av.w;
        Bs[lk + 0][lrow] = bv.x; Bs[lk + 1][lrow] = bv.y;
        Bs[lk + 2][lrow] = bv.z; Bs[lk + 3][lrow] = bv.w;
        __syncthreads();
#pragma unroll
        for (int kk = 0; kk < 16; ++kk) {
            float4 a = *(const float4*)&As[kk][ty * 4];
            float4 b = *(const float4*)&Bs[kk][tx * 4];
            float aa[4] = {a.x, a.y, a.z, a.w};
            float bb[4] = {b.x, b.y, b.z, b.w};
#pragma unroll
            for (int i = 0; i < 4; ++i)
#pragma unroll
                for (int j = 0; j < 4; ++j)
                    acc[i][j] = fmaf(aa[i], bb[j], acc[i][j]);
        }
    }

    float4 bb4 = *(const float4*)(bi + n0 + tx * 4);
    float bArr[4] = {bb4.x, bb4.y, bb4.z, bb4.w};
#pragma unroll
    for (int i = 0; i < 4; ++i) {
        float4 o;
        o.x = acc[i][0] + bArr[0];
        o.y = acc[i][1] + bArr[1];
        o.z = acc[i][2] + bArr[2];
        o.w = acc[i][3] + bArr[3];
        *(float4*)(xp + (size_t)(m0 + ty * 4 + i) * kTH + n0 + tx * 4) = o;
    }
}

// Persistent GRU. 256 blocks x 512 threads, 1 block/CU.
// Block b: sequence s=b>>7, owns h[i0..i0+16), i0=(b&127)*16.
// Wave w owns rows {g*kH + i0 + 2w + jj : g in 0..2, jj in 0..1}; lane l
// covers cols e*256+4l..+3.
__global__ __launch_bounds__(512, 2) void gru_pair_kernel(
    const float* __restrict__ xp1, const float* __restrict__ xp2,
    const float* __restrict__ Whh1, const float* __restrict__ Whh2,
    const float* __restrict__ bhh1, const float* __restrict__ bhh2,
    unsigned long long* __restrict__ pub,   // [2 seq][2 parity][kH]
    unsigned* __restrict__ sync,            // flags, 64-B stride
    float* __restrict__ hfinal) {           // [2 seq][kH]
    const int tid  = threadIdx.x;
    const int lane = tid & 63;
    const int wv   = tid >> 6;          // 0..7
    const int b    = blockIdx.x;
    const int s    = b >> 7;
    const int lb   = b & 127;
    const int i0   = lb * 16;
    const float* xp  = s ? xp2  : xp1;
    const float* Whh = s ? Whh2 : Whh1;
    const float* bhh = s ? bhh2 : bhh1;
    unsigned long long* pubs = pub + (size_t)s * 2 * kH;
    unsigned* flags = sync + s * 2048;      // flag[j] at flags[j*16]

    __shared__ float h_s[kH];
    __shared__ float hn_s[16];
    __shared__ float xp_s[2][48];       // [parity][g*16+elem]

    // one-time register-resident weight load: p = g*2+jj
    float w[6][32];
    float bias[6];
#pragma unroll
    for (int p = 0; p < 6; ++p) {
        const int g  = p >> 1, jj = p & 1;
        const int rg = g * kH + i0 + wv * 2 + jj;
        bias[p] = bhh[rg];
        const float* wr = Whh + (size_t)rg * kH;
#pragma unroll
        for (int e = 0; e < 8; ++e) {
            float4 v = *(const float4*)(wr + e * 256 + lane * 4);
            w[p][e * 4 + 0] = v.x; w[p][e * 4 + 1] = v.y;
            w[p][e * 4 + 2] = v.z; w[p][e * 4 + 3] = v.w;
        }
    }
    *(float4*)&h_s[tid * 4] = make_float4(0.f, 0.f, 0.f, 0.f);
    if (tid < 48) {                     // stage xp[0]
        xp_s[0][tid] = xp[(size_t)(tid >> 4) * kH + i0 + (tid & 15)];
    }
    __syncthreads();

    const int base = tid * 4;

    for (int t = 0; t < kT; ++t) {
        const int parC = t & 1;
        const int parN = parC ^ 1;

        // wave 2: issue xp[t+1] loads early (latency hides under matvec)
        float xpv = 0.f;
        if (wv == 2 && lane < 48 && t + 1 < kT) {
            xpv = xp[(size_t)(t + 1) * kTH + (size_t)(lane >> 4) * kH + i0 +
                     (lane & 15)];
        }

        // matvec: 6 rows (3 gates x 2 elems), weights in regs, h from LDS
        float a0 = 0.f, a1 = 0.f, a2 = 0.f, a3 = 0.f, a4 = 0.f, a5 = 0.f;
#pragma unroll
        for (int e = 0; e < 8; ++e) {
            const float4 hv = *(const float4*)&h_s[e * 256 + lane * 4];
            a0 = fmaf(w[0][e * 4 + 0], hv.x, a0);
            a0 = fmaf(w[0][e * 4 + 1], hv.y, a0);
            a0 = fmaf(w[0][e * 4 + 2], hv.z, a0);
            a0 = fmaf(w[0][e * 4 + 3], hv.w, a0);
            a1 = fmaf(w[1][e * 4 + 0], hv.x, a1);
            a1 = fmaf(w[1][e * 4 + 1], hv.y, a1);
            a1 = fmaf(w[1][e * 4 + 2], hv.z, a1);
            a1 = fmaf(w[1][e * 4 + 3], hv.w, a1);
            a2 = fmaf(w[2][e * 4 + 0], hv.x, a2);
            a2 = fmaf(w[2][e * 4 + 1], hv.y, a2);
            a2 = fmaf(w[2][e * 4 + 2], hv.z, a2);
            a2 = fmaf(w[2][e * 4 + 3], hv.w, a2);
            a3 = fmaf(w[3][e * 4 + 0], hv.x, a3);
            a3 = fmaf(w[3][e * 4 + 1], hv.y, a3);
            a3 = fmaf(w[3][e * 4 + 2], hv.z, a3);
            a3 = fmaf(w[3][e * 4 + 3], hv.w, a3);
            a4 = fmaf(w[4][e * 4 + 0], hv.x, a4);
            a4 = fmaf(w[4][e * 4 + 1], hv.y, a4);
            a4 = fmaf(w[4][e * 4 + 2], hv.z, a4);
            a4 = fmaf(w[4][e * 4 + 3], hv.w, a4);
            a5 = fmaf(w[5][e * 4 + 0], hv.x, a5);
            a5 = fmaf(w[5][e * 4 + 1], hv.y, a5);
            a5 = fmaf(w[5][e * 4 + 2], hv.z, a5);
            a5 = fmaf(w[5][e * 4 + 3], hv.w, a5);
        }
        // shfl_down reduce (same tree as prior rounds -> bit-identical)
        float acc6[6] = {a0, a1, a2, a3, a4, a5};
#pragma unroll
        for (int p = 0; p < 6; ++p) {
            float a = acc6[p];
#pragma unroll
            for (int off = 32; off; off >>= 1) a += __shfl_down(a, off, 64);
            acc6[p] = a;                // valid on lane 0
        }
        // broadcast reduced sums; lanes 0-1 compute gates in parallel
        const float s0 = __shfl(acc6[0], 0, 64);
        const float s1 = __shfl(acc6[1], 0, 64);
        const float s2 = __shfl(acc6[2], 0, 64);
        const float s3 = __shfl(acc6[3], 0, 64);
        const float s4 = __shfl(acc6[4], 0, 64);
        const float s5 = __shfl(acc6[5], 0, 64);
        if (lane < 2) {
            const int le = wv * 2 + lane;     // local elem 0..15
            const int i  = i0 + le;
            const float hr  = (lane ? s1 : s0) + (lane ? bias[1] : bias[0]);
            const float hz  = (lane ? s3 : s2) + (lane ? bias[3] : bias[2]);
            const float hnp = (lane ? s5 : s4) + (lane ? bias[5] : bias[4]);
            const float xr = xp_s[parC][le];
            const float xz = xp_s[parC][16 + le];
            const float xn = xp_s[parC][32 + le];
            const float r = 1.f / (1.f + expf(-(xr + hr)));
            const float z = 1.f / (1.f + expf(-(xz + hz)));
            const float n = tanhf(xn + r * hnp);
            const float hn = (1.f - z) * n + z * h_s[i];
            if (t == kT - 1) hfinal[s * kH + i] = hn;
            else             hn_s[le] = hn;
        }
        if (t == kT - 1) break;
        __syncthreads();   // (A) hn_s complete; h_s/xp_s reads done

        unsigned long long* dst = pubs + (size_t)parN * kH;
        if (wv == 0) {
            // ONE coalesced 128-B tagged store (single line, single writer),
            // then flag hint. No vmcnt: tags carry correctness.
            if (lane < 16) {
                const unsigned long long pk =
                    ((unsigned long long)(unsigned)(t + 1) << 32) |
                    (unsigned long long)__float_as_uint(hn_s[lane]);
                __hip_atomic_store(&dst[i0 + lane], pk, __ATOMIC_RELAXED,
                                   __HIP_MEMORY_SCOPE_AGENT);
            }
            if (lane == 0) {
                __hip_atomic_store(&flags[lb * 16], (unsigned)(t + 1),
                                   __ATOMIC_RELAXED, __HIP_MEMORY_SCOPE_AGENT);
            }
        } else if (wv == 1) {
            // poll dedicated flag lines only (written once/step each)
            const unsigned tgt = (unsigned)(t + 1);
            const unsigned* fa = flags + lane * 16;
            const unsigned* fb = flags + (lane + 64) * 16;
            for (;;) {
                unsigned f1 = __hip_atomic_load(fa, __ATOMIC_RELAXED,
                                                __HIP_MEMORY_SCOPE_AGENT);
                unsigned f2 = __hip_atomic_load(fb, __ATOMIC_RELAXED,
                                                __HIP_MEMORY_SCOPE_AGENT);
                if (__all((f1 >= tgt) && (f2 >= tgt))) break;
                __builtin_amdgcn_s_sleep(1);
            }
        } else if (wv == 2) {
            if (lane < 48) xp_s[parN][lane] = xpv;
        }
        __syncthreads();   // (B) flags seen -> publishes ~visible

        // bulk load: 4 tagged words/thread, verify (>=), selective retry
        {
            const unsigned tgt = (unsigned)(t + 1);
            unsigned long long v0, v1, v2, v3;
            v0 = __hip_atomic_load(&dst[base + 0], __ATOMIC_RELAXED,
                                   __HIP_MEMORY_SCOPE_AGENT);
            v1 = __hip_atomic_load(&dst[base + 1], __ATOMIC_RELAXED,
                                   __HIP_MEMORY_SCOPE_AGENT);
            v2 = __hip_atomic_load(&dst[base + 2], __ATOMIC_RELAXED,
                                   __HIP_MEMORY_SCOPE_AGENT);
            v3 = __hip_atomic_load(&dst[base + 3], __ATOMIC_RELAXED,
                                   __HIP_MEMORY_SCOPE_AGENT);
            bool d0 = (unsigned)(v0 >> 32) >= tgt;
            bool d1 = (unsigned)(v1 >> 32) >= tgt;
            bool d2 = (unsigned)(v2 >> 32) >= tgt;
            bool d3 = (unsigned)(v3 >> 32) >= tgt;
            while (!(d0 & d1 & d2 & d3)) {
                __builtin_amdgcn_s_sleep(1);
                if (!d0) { v0 = __hip_atomic_load(&dst[base + 0], __ATOMIC_RELAXED, __HIP_MEMORY_SCOPE_AGENT); d0 = (unsigned)(v0 >> 32) >= tgt; }
                if (!d1) { v1 = __hip_atomic_load(&dst[base + 1], __ATOMIC_RELAXED, __HIP_MEMORY_SCOPE_AGENT); d1 = (unsigned)(v1 >> 32) >= tgt; }
                if (!d2) { v2 = __hip_atomic_load(&dst[base + 2], __ATOMIC_RELAXED, __HIP_MEMORY_SCOPE_AGENT); d2 = (unsigned)(v2 >> 32) >= tgt; }
                if (!d3) { v3 = __hip_atomic_load(&dst[base + 3], __ATOMIC_RELAXED, __HIP_MEMORY_SCOPE_AGENT); d3 = (unsigned)(v3 >> 32) >= tgt; }
            }
            float4 hv;
            hv.x = __uint_as_float((unsigned)v0);
            hv.y = __uint_as_float((unsigned)v1);
            hv.z = __uint_as_float((unsigned)v2);
            hv.w = __uint_as_float((unsigned)v3);
            *(float4*)&h_s[base] = hv;
        }
        __syncthreads();   // (C) h_s ready for next matvec
    }
}

// fc1(relu) -> fc2 -> log_softmax, single block of 256 threads
__global__ __launch_bounds__(256) void head_kernel(
    const float* __restrict__ h1, const float* __restrict__ h2,
    const float* __restrict__ fc1w, const float* __restrict__ fc1b,
    const float* __restrict__ fc2w, const float* __restrict__ fc2b,
    float* __restrict__ out) {
    __shared__ float cat[2 * kH];
    __shared__ float o1[256];
    __shared__ float logits[3];
    const int tid  = threadIdx.x;
    const int lane = tid & 63;
    const int wave = tid >> 6;

    for (int k = tid; k < kH; k += 256) {
        cat[k]      = h1[k];
        cat[kH + k] = h2[k];
    }
    __syncthreads();

    for (int r = wave; r < 256; r += 4) {
        const float* wr = fc1w + (size_t)r * (2 * kH);
        float acc = 0.f;
        for (int j = lane; j < 2 * kH; j += 64) acc = fmaf(wr[j], cat[j], acc);
#pragma unroll
        for (int off = 32; off; off >>= 1) acc += __shfl_down(acc, off, 64);
        if (lane == 0) o1[r] = fmaxf(acc + fc1b[r], 0.f);
    }
    __syncthreads();

    if (tid < 3) {
        float acc = fc2b[tid];
        const float* wr = fc2w + tid * 256;
        for (int j = 0; j < 256; ++j) acc = fmaf(wr[j], o1[j], acc);
        logits[tid] = acc;
    }
    __syncthreads();

    if (tid == 0) {
        float m = fmaxf(logits[0], fmaxf(logits[1], logits[2]));
        float s = expf(logits[0] - m) + expf(logits[1] - m) + expf(logits[2] - m);
        float ls = logf(s);
        out[0] = logits[0] - m - ls;
        out[1] = logits[1] - m - ls;
        out[2] = logits[2] - m - ls;
    }
}

extern "C" void kernel_launch(void* const* d_in, const int* in_sizes, int n_in,
                              void* d_out, int out_size, void* d_ws,
                              size_t ws_size, hipStream_t stream) {
    const float* x1   = (const float*)d_in[0];
    const float* x2   = (const float*)d_in[1];
    const float* Wih1 = (const float*)d_in[2];
    const float* Whh1 = (const float*)d_in[3];
    const float* bih1 = (const float*)d_in[4];
    const float* bhh1 = (const float*)d_in[5];
    const float* Wih2 = (const float*)d_in[6];
    const float* Whh2 = (const float*)d_in[7];
    const float* bih2 = (const float*)d_in[8];
    const float* bhh2 = (const float*)d_in[9];
    const float* fc1w = (const float*)d_in[10];
    const float* fc1b = (const float*)d_in[11];
    const float* fc2w = (const float*)d_in[12];
    const float* fc2b = (const float*)d_in[13];
    float* out = (float*)d_out;

    char* ws = (char*)d_ws;
    float* xp1 = (float*)ws;
    float* xp2 = xp1 + (size_t)kT * kTH;
    unsigned long long* pub = (unsigned long long*)(xp2 + (size_t)kT * kTH);
    unsigned* sync = (unsigned*)(pub + 4 * kH);
    float* hfinal = (float*)(sync + 4096);   // [2][kH]

    init_ws_kernel<<<8, 1024, 0, stream>>>(pub, sync);

    gemm_xp_kernel<<<dim3(kTH / 64, kT / 64, 2), 256, 0, stream>>>(
        x1, x2, Wih1, Wih2, bih1, bih2, xp1, xp2);

    gru_pair_kernel<<<dim3(kNB), dim3(512), 0, stream>>>(
        xp1, xp2, Whh1, Whh2, bhh1, bhh2, pub, sync, hfinal);

    head_kernel<<<1, 256, 0, stream>>>(hfinal, hfinal + kH, fc1w, fc1b, fc2w,
                                       fc2b, out);
}

// Round 7
// 19318.433 us; speedup vs baseline: 1.4270x; 1.0299x over previous
//
#include <hip/hip_runtime.h>
#include <hip/hip_bf16.h>

// Problem dims
constexpr int kH  = 2048;          // hidden
constexpr int kD  = 1024;          // input dim
constexpr int kT  = 4096;          // timesteps
constexpr int kTH = 3 * kH;        // 6144 gate rows
constexpr int kNB = 256;           // GRU grid blocks (128 per sequence)

// ---------------------------------------------------------------------------
// Round-13 post-mortem (container failed twice, no profile): REAL BUG found
// in the new 128x128 gemm -- LDS pad of +2 gave row stride 130 floats =
// 520 B = 8 (mod 16). `*(float4*)&As[kk][ty*8]` at odd kk is then only 8-B
// aligned while the cast promises 16 -> ds_read_b128 misaligned = UB/fault.
// (r12's 64x64 kernel was safe by accident: 68-float pad = 272 B = 0 mod 16.)
// Round-14: identical design with pad 132 (stride 528 B, 16-B aligned for
// every float4 read). Bank geometry at stride 132: A-side reads are 16-lane
// broadcast groups on disjoint bank quads (conflict-free); B-side is 4-way
// (1.58x on LDS pipe, m136) but the loop is FMA-bound (64 FMA per 4 b128
// reads) so it stays hidden. GRU kernel byte-identical to r12 (16.95 ms,
// 4.14 us/step, rendezvous at ~2 LLC round trips = near structural floor).
// Bit-exact: one accumulator per output, fmaf over strictly ascending k,
// same k0/kk nesting as all prior rounds -> absmax 0.0 preserved.
// ---------------------------------------------------------------------------

__global__ void init_ws_kernel(unsigned long long* __restrict__ pub,
                               unsigned* __restrict__ sync) {
    const int i = blockIdx.x * 1024 + threadIdx.x;
    if (i < 8192) pub[i] = 0ull;        // [2 seq][2 parity][kH]
    if (i < 4096) sync[i] = 0u;         // flag lines, 64-B stride
}

// fp32 tiled GEMM: xp[t][j] = sum_k x[t][k] * Wih[j][k] + bih[j]
// 128x128 tile, BK=16, 256 threads, 8x8 outputs/thread.
__global__ __launch_bounds__(256, 2) void gemm_xp_kernel(
    const float* __restrict__ x1, const float* __restrict__ x2,
    const float* __restrict__ Wih1, const float* __restrict__ Wih2,
    const float* __restrict__ bih1, const float* __restrict__ bih2,
    float* __restrict__ xp1, float* __restrict__ xp2) {
    const float* x  = blockIdx.z ? x2   : x1;
    const float* W  = blockIdx.z ? Wih2 : Wih1;
    const float* bi = blockIdx.z ? bih2 : bih1;
    float*       xp = blockIdx.z ? xp2  : xp1;

    // pad 132: row stride 528 B = 33*16 -> every float4 read 16-B aligned
    __shared__ float As[16][132];       // [kk][row in tile]
    __shared__ float Bs[16][132];

    const int tid  = threadIdx.x;
    const int tx   = tid & 15;          // 0..15 -> 8 cols each
    const int ty   = tid >> 4;          // 0..15 -> 8 rows each
    const int lrow = tid >> 2;          // 0..63 staging row
    const int lk   = (tid & 3) * 4;     // staging k offset
    const int m0   = blockIdx.y * 128;  // t-tile
    const int n0   = blockIdx.x * 128;  // gate-row tile

    float acc[8][8] = {};

    for (int k0 = 0; k0 < kD; k0 += 16) {
        // stage A (x rows) and B (W rows): 2 float4 each per thread
        float4 a0 = *(const float4*)(x + (size_t)(m0 + lrow) * kD + k0 + lk);
        float4 a1 = *(const float4*)(x + (size_t)(m0 + lrow + 64) * kD + k0 + lk);
        float4 b0 = *(const float4*)(W + (size_t)(n0 + lrow) * kD + k0 + lk);
        float4 b1 = *(const float4*)(W + (size_t)(n0 + lrow + 64) * kD + k0 + lk);
        __syncthreads();
        As[lk + 0][lrow] = a0.x; As[lk + 1][lrow] = a0.y;
        As[lk + 2][lrow] = a0.z; As[lk + 3][lrow] = a0.w;
        As[lk + 0][lrow + 64] = a1.x; As[lk + 1][lrow + 64] = a1.y;
        As[lk + 2][lrow + 64] = a1.z; As[lk + 3][lrow + 64] = a1.w;
        Bs[lk + 0][lrow] = b0.x; Bs[lk + 1][lrow] = b0.y;
        Bs[lk + 2][lrow] = b0.z; Bs[lk + 3][lrow] = b0.w;
        Bs[lk + 0][lrow + 64] = b1.x; Bs[lk + 1][lrow + 64] = b1.y;
        Bs[lk + 2][lrow + 64] = b1.z; Bs[lk + 3][lrow + 64] = b1.w;
        __syncthreads();
#pragma unroll
        for (int kk = 0; kk < 16; ++kk) {
            float4 av0 = *(const float4*)&As[kk][ty * 8];
            float4 av1 = *(const float4*)&As[kk][ty * 8 + 4];
            float4 bv0 = *(const float4*)&Bs[kk][tx * 8];
            float4 bv1 = *(const float4*)&Bs[kk][tx * 8 + 4];
            float aa[8] = {av0.x, av0.y, av0.z, av0.w,
                           av1.x, av1.y, av1.z, av1.w};
            float bb[8] = {bv0.x, bv0.y, bv0.z, bv0.w,
                           bv1.x, bv1.y, bv1.z, bv1.w};
#pragma unroll
            for (int i = 0; i < 8; ++i)
#pragma unroll
                for (int j = 0; j < 8; ++j)
                    acc[i][j] = fmaf(aa[i], bb[j], acc[i][j]);
        }
    }

    // bias + store: rows m0+ty*8+i, cols n0+tx*8+j
    float4 bb40 = *(const float4*)(bi + n0 + tx * 8);
    float4 bb41 = *(const float4*)(bi + n0 + tx * 8 + 4);
    float bArr[8] = {bb40.x, bb40.y, bb40.z, bb40.w,
                     bb41.x, bb41.y, bb41.z, bb41.w};
#pragma unroll
    for (int i = 0; i < 8; ++i) {
        float* orow = xp + (size_t)(m0 + ty * 8 + i) * kTH + n0 + tx * 8;
        float4 o0, o1;
        o0.x = acc[i][0] + bArr[0];
        o0.y = acc[i][1] + bArr[1];
        o0.z = acc[i][2] + bArr[2];
        o0.w = acc[i][3] + bArr[3];
        o1.x = acc[i][4] + bArr[4];
        o1.y = acc[i][5] + bArr[5];
        o1.z = acc[i][6] + bArr[6];
        o1.w = acc[i][7] + bArr[7];
        *(float4*)(orow)     = o0;
        *(float4*)(orow + 4) = o1;
    }
}

// Persistent GRU. 256 blocks x 512 threads, 1 block/CU.
// Block b: sequence s=b>>7, owns h[i0..i0+16), i0=(b&127)*16.
// Wave w owns rows {g*kH + i0 + 2w + jj : g in 0..2, jj in 0..1}; lane l
// covers cols e*256+4l..+3.
__global__ __launch_bounds__(512, 2) void gru_pair_kernel(
    const float* __restrict__ xp1, const float* __restrict__ xp2,
    const float* __restrict__ Whh1, const float* __restrict__ Whh2,
    const float* __restrict__ bhh1, const float* __restrict__ bhh2,
    unsigned long long* __restrict__ pub,   // [2 seq][2 parity][kH]
    unsigned* __restrict__ sync,            // flags, 64-B stride
    float* __restrict__ hfinal) {           // [2 seq][kH]
    const int tid  = threadIdx.x;
    const int lane = tid & 63;
    const int wv   = tid >> 6;          // 0..7
    const int b    = blockIdx.x;
    const int s    = b >> 7;
    const int lb   = b & 127;
    const int i0   = lb * 16;
    const float* xp  = s ? xp2  : xp1;
    const float* Whh = s ? Whh2 : Whh1;
    const float* bhh = s ? bhh2 : bhh1;
    unsigned long long* pubs = pub + (size_t)s * 2 * kH;
    unsigned* flags = sync + s * 2048;      // flag[j] at flags[j*16]

    __shared__ float h_s[kH];
    __shared__ float hn_s[16];
    __shared__ float xp_s[2][48];       // [parity][g*16+elem]

    // one-time register-resident weight load: p = g*2+jj
    float w[6][32];
    float bias[6];
#pragma unroll
    for (int p = 0; p < 6; ++p) {
        const int g  = p >> 1, jj = p & 1;
        const int rg = g * kH + i0 + wv * 2 + jj;
        bias[p] = bhh[rg];
        const float* wr = Whh + (size_t)rg * kH;
#pragma unroll
        for (int e = 0; e < 8; ++e) {
            float4 v = *(const float4*)(wr + e * 256 + lane * 4);
            w[p][e * 4 + 0] = v.x; w[p][e * 4 + 1] = v.y;
            w[p][e * 4 + 2] = v.z; w[p][e * 4 + 3] = v.w;
        }
    }
    *(float4*)&h_s[tid * 4] = make_float4(0.f, 0.f, 0.f, 0.f);
    if (tid < 48) {                     // stage xp[0]
        xp_s[0][tid] = xp[(size_t)(tid >> 4) * kH + i0 + (tid & 15)];
    }
    __syncthreads();

    const int base = tid * 4;

    for (int t = 0; t < kT; ++t) {
        const int parC = t & 1;
        const int parN = parC ^ 1;

        // wave 2: issue xp[t+1] loads early (latency hides under matvec)
        float xpv = 0.f;
        if (wv == 2 && lane < 48 && t + 1 < kT) {
            xpv = xp[(size_t)(t + 1) * kTH + (size_t)(lane >> 4) * kH + i0 +
                     (lane & 15)];
        }

        // matvec: 6 rows (3 gates x 2 elems), weights in regs, h from LDS
        float a0 = 0.f, a1 = 0.f, a2 = 0.f, a3 = 0.f, a4 = 0.f, a5 = 0.f;
#pragma unroll
        for (int e = 0; e < 8; ++e) {
            const float4 hv = *(const float4*)&h_s[e * 256 + lane * 4];
            a0 = fmaf(w[0][e * 4 + 0], hv.x, a0);
            a0 = fmaf(w[0][e * 4 + 1], hv.y, a0);
            a0 = fmaf(w[0][e * 4 + 2], hv.z, a0);
            a0 = fmaf(w[0][e * 4 + 3], hv.w, a0);
            a1 = fmaf(w[1][e * 4 + 0], hv.x, a1);
            a1 = fmaf(w[1][e * 4 + 1], hv.y, a1);
            a1 = fmaf(w[1][e * 4 + 2], hv.z, a1);
            a1 = fmaf(w[1][e * 4 + 3], hv.w, a1);
            a2 = fmaf(w[2][e * 4 + 0], hv.x, a2);
            a2 = fmaf(w[2][e * 4 + 1], hv.y, a2);
            a2 = fmaf(w[2][e * 4 + 2], hv.z, a2);
            a2 = fmaf(w[2][e * 4 + 3], hv.w, a2);
            a3 = fmaf(w[3][e * 4 + 0], hv.x, a3);
            a3 = fmaf(w[3][e * 4 + 1], hv.y, a3);
            a3 = fmaf(w[3][e * 4 + 2], hv.z, a3);
            a3 = fmaf(w[3][e * 4 + 3], hv.w, a3);
            a4 = fmaf(w[4][e * 4 + 0], hv.x, a4);
            a4 = fmaf(w[4][e * 4 + 1], hv.y, a4);
            a4 = fmaf(w[4][e * 4 + 2], hv.z, a4);
            a4 = fmaf(w[4][e * 4 + 3], hv.w, a4);
            a5 = fmaf(w[5][e * 4 + 0], hv.x, a5);
            a5 = fmaf(w[5][e * 4 + 1], hv.y, a5);
            a5 = fmaf(w[5][e * 4 + 2], hv.z, a5);
            a5 = fmaf(w[5][e * 4 + 3], hv.w, a5);
        }
        // shfl_down reduce (same tree as prior rounds -> bit-identical)
        float acc6[6] = {a0, a1, a2, a3, a4, a5};
#pragma unroll
        for (int p = 0; p < 6; ++p) {
            float a = acc6[p];
#pragma unroll
            for (int off = 32; off; off >>= 1) a += __shfl_down(a, off, 64);
            acc6[p] = a;                // valid on lane 0
        }
        // broadcast reduced sums; lanes 0-1 compute gates in parallel
        const float s0 = __shfl(acc6[0], 0, 64);
        const float s1 = __shfl(acc6[1], 0, 64);
        const float s2 = __shfl(acc6[2], 0, 64);
        const float s3 = __shfl(acc6[3], 0, 64);
        const float s4 = __shfl(acc6[4], 0, 64);
        const float s5 = __shfl(acc6[5], 0, 64);
        if (lane < 2) {
            const int le = wv * 2 + lane;     // local elem 0..15
            const int i  = i0 + le;
            const float hr  = (lane ? s1 : s0) + (lane ? bias[1] : bias[0]);
            const float hz  = (lane ? s3 : s2) + (lane ? bias[3] : bias[2]);
            const float hnp = (lane ? s5 : s4) + (lane ? bias[5] : bias[4]);
            const float xr = xp_s[parC][le];
            const float xz = xp_s[parC][16 + le];
            const float xn = xp_s[parC][32 + le];
            const float r = 1.f / (1.f + expf(-(xr + hr)));
            const float z = 1.f / (1.f + expf(-(xz + hz)));
            const float n = tanhf(xn + r * hnp);
            const float hn = (1.f - z) * n + z * h_s[i];
            if (t == kT - 1) hfinal[s * kH + i] = hn;
            else             hn_s[le] = hn;
        }
        if (t == kT - 1) break;
        __syncthreads();   // (A) hn_s complete; h_s/xp_s reads done

        unsigned long long* dst = pubs + (size_t)parN * kH;
        if (wv == 0) {
            // ONE coalesced 128-B tagged store (single line, single writer),
            // then flag hint. No vmcnt: tags carry correctness.
            if (lane < 16) {
                const unsigned long long pk =
                    ((unsigned long long)(unsigned)(t + 1) << 32) |
                    (unsigned long long)__float_as_uint(hn_s[lane]);
                __hip_atomic_store(&dst[i0 + lane], pk, __ATOMIC_RELAXED,
                                   __HIP_MEMORY_SCOPE_AGENT);
            }
            if (lane == 0) {
                __hip_atomic_store(&flags[lb * 16], (unsigned)(t + 1),
                                   __ATOMIC_RELAXED, __HIP_MEMORY_SCOPE_AGENT);
            }
        } else if (wv == 1) {
            // poll dedicated flag lines only (written once/step each)
            const unsigned tgt = (unsigned)(t + 1);
            const unsigned* fa = flags + lane * 16;
            const unsigned* fb = flags + (lane + 64) * 16;
            for (;;) {
                unsigned f1 = __hip_atomic_load(fa, __ATOMIC_RELAXED,
                                                __HIP_MEMORY_SCOPE_AGENT);
                unsigned f2 = __hip_atomic_load(fb, __ATOMIC_RELAXED,
                                                __HIP_MEMORY_SCOPE_AGENT);
                if (__all((f1 >= tgt) && (f2 >= tgt))) break;
                __builtin_amdgcn_s_sleep(1);
            }
        } else if (wv == 2) {
            if (lane < 48) xp_s[parN][lane] = xpv;
        }
        __syncthreads();   // (B) flags seen -> publishes ~visible

        // bulk load: 4 tagged words/thread, verify (>=), selective retry
        {
            const unsigned tgt = (unsigned)(t + 1);
            unsigned long long v0, v1, v2, v3;
            v0 = __hip_atomic_load(&dst[base + 0], __ATOMIC_RELAXED,
                                   __HIP_MEMORY_SCOPE_AGENT);
            v1 = __hip_atomic_load(&dst[base + 1], __ATOMIC_RELAXED,
                                   __HIP_MEMORY_SCOPE_AGENT);
            v2 = __hip_atomic_load(&dst[base + 2], __ATOMIC_RELAXED,
                                   __HIP_MEMORY_SCOPE_AGENT);
            v3 = __hip_atomic_load(&dst[base + 3], __ATOMIC_RELAXED,
                                   __HIP_MEMORY_SCOPE_AGENT);
            bool d0 = (unsigned)(v0 >> 32) >= tgt;
            bool d1 = (unsigned)(v1 >> 32) >= tgt;
            bool d2 = (unsigned)(v2 >> 32) >= tgt;
            bool d3 = (unsigned)(v3 >> 32) >= tgt;
            while (!(d0 & d1 & d2 & d3)) {
                __builtin_amdgcn_s_sleep(1);
                if (!d0) { v0 = __hip_atomic_load(&dst[base + 0], __ATOMIC_RELAXED, __HIP_MEMORY_SCOPE_AGENT); d0 = (unsigned)(v0 >> 32) >= tgt; }
                if (!d1) { v1 = __hip_atomic_load(&dst[base + 1], __ATOMIC_RELAXED, __HIP_MEMORY_SCOPE_AGENT); d1 = (unsigned)(v1 >> 32) >= tgt; }
                if (!d2) { v2 = __hip_atomic_load(&dst[base + 2], __ATOMIC_RELAXED, __HIP_MEMORY_SCOPE_AGENT); d2 = (unsigned)(v2 >> 32) >= tgt; }
                if (!d3) { v3 = __hip_atomic_load(&dst[base + 3], __ATOMIC_RELAXED, __HIP_MEMORY_SCOPE_AGENT); d3 = (unsigned)(v3 >> 32) >= tgt; }
            }
            float4 hv;
            hv.x = __uint_as_float((unsigned)v0);
            hv.y = __uint_as_float((unsigned)v1);
            hv.z = __uint_as_float((unsigned)v2);
            hv.w = __uint_as_float((unsigned)v3);
            *(float4*)&h_s[base] = hv;
        }
        __syncthreads();   // (C) h_s ready for next matvec
    }
}

// fc1(relu) -> fc2 -> log_softmax, single block of 256 threads
__global__ __launch_bounds__(256) void head_kernel(
    const float* __restrict__ h1, const float* __restrict__ h2,
    const float* __restrict__ fc1w, const float* __restrict__ fc1b,
    const float* __restrict__ fc2w, const float* __restrict__ fc2b,
    float* __restrict__ out) {
    __shared__ float cat[2 * kH];
    __shared__ float o1[256];
    __shared__ float logits[3];
    const int tid  = threadIdx.x;
    const int lane = tid & 63;
    const int wave = tid >> 6;

    for (int k = tid; k < kH; k += 256) {
        cat[k]      = h1[k];
        cat[kH + k] = h2[k];
    }
    __syncthreads();

    for (int r = wave; r < 256; r += 4) {
        const float* wr = fc1w + (size_t)r * (2 * kH);
        float acc = 0.f;
        for (int j = lane; j < 2 * kH; j += 64) acc = fmaf(wr[j], cat[j], acc);
#pragma unroll
        for (int off = 32; off; off >>= 1) acc += __shfl_down(acc, off, 64);
        if (lane == 0) o1[r] = fmaxf(acc + fc1b[r], 0.f);
    }
    __syncthreads();

    if (tid < 3) {
        float acc = fc2b[tid];
        const float* wr = fc2w + tid * 256;
        for (int j = 0; j < 256; ++j) acc = fmaf(wr[j], o1[j], acc);
        logits[tid] = acc;
    }
    __syncthreads();

    if (tid == 0) {
        float m = fmaxf(logits[0], fmaxf(logits[1], logits[2]));
        float s = expf(logits[0] - m) + expf(logits[1] - m) + expf(logits[2] - m);
        float ls = logf(s);
        out[0] = logits[0] - m - ls;
        out[1] = logits[1] - m - ls;
        out[2] = logits[2] - m - ls;
    }
}

extern "C" void kernel_launch(void* const* d_in, const int* in_sizes, int n_in,
                              void* d_out, int out_size, void* d_ws,
                              size_t ws_size, hipStream_t stream) {
    const float* x1   = (const float*)d_in[0];
    const float* x2   = (const float*)d_in[1];
    const float* Wih1 = (const float*)d_in[2];
    const float* Whh1 = (const float*)d_in[3];
    const float* bih1 = (const float*)d_in[4];
    const float* bhh1 = (const float*)d_in[5];
    const float* Wih2 = (const float*)d_in[6];
    const float* Whh2 = (const float*)d_in[7];
    const float* bih2 = (const float*)d_in[8];
    const float* bhh2 = (const float*)d_in[9];
    const float* fc1w = (const float*)d_in[10];
    const float* fc1b = (const float*)d_in[11];
    const float* fc2w = (const float*)d_in[12];
    const float* fc2b = (const float*)d_in[13];
    float* out = (float*)d_out;

    char* ws = (char*)d_ws;
    float* xp1 = (float*)ws;
    float* xp2 = xp1 + (size_t)kT * kTH;
    unsigned long long* pub = (unsigned long long*)(xp2 + (size_t)kT * kTH);
    unsigned* sync = (unsigned*)(pub + 4 * kH);
    float* hfinal = (float*)(sync + 4096);   // [2][kH]

    init_ws_kernel<<<8, 1024, 0, stream>>>(pub, sync);

    gemm_xp_kernel<<<dim3(kTH / 128, kT / 128, 2), 256, 0, stream>>>(
        x1, x2, Wih1, Wih2, bih1, bih2, xp1, xp2);

    gru_pair_kernel<<<dim3(kNB), dim3(512), 0, stream>>>(
        xp1, xp2, Whh1, Whh2, bhh1, bhh2, pub, sync, hfinal);

    head_kernel<<<1, 256, 0, stream>>>(hfinal, hfinal + kH, fc1w, fc1b, fc2w,
                                       fc2b, out);
}